// Round 1
// baseline (1720.439 us; speedup 1.0000x reference)
//
#include <hip/hip_runtime.h>
#include <hip/hip_bf16.h>
#include <math.h>

#define NHEADS 8
#define HDIM   32
#define HALFD  16
#define DB     2
#define DH     512
#define DW     64
#define DC     256
#define NTOK   (DB*DW*DH)   /* 65536 tokens, t = (b*64+w)*512 + h */

typedef unsigned short u16;
typedef unsigned int   u32;

__device__ __forceinline__ float bf_lo(u32 u){ union{u32 i; float f;} c; c.i = u << 16; return c.f; }
__device__ __forceinline__ float bf_hi(u32 u){ union{u32 i; float f;} c; c.i = u & 0xffff0000u; return c.f; }
__device__ __forceinline__ float bfu(u16 u){ union{u32 i; float f;} c; c.i = ((u32)u) << 16; return c.f; }
__device__ __forceinline__ u16 f2bf(float f){
    u32 x = __float_as_uint(f);
    u32 r = (x + 0x7fffu + ((x >> 16) & 1u)) >> 16;   // RTN-even
    return (u16)r;
}

// ---------------------------------------------------------------------------
// Kernel 0: cos/sin table  [b][h][n][j]  (131072 entries each)
// ---------------------------------------------------------------------------
__global__ void __launch_bounds__(256) rope_table_kernel(
    const float* __restrict__ pos, const float* __restrict__ rope_w,
    const float* __restrict__ rope_b, float* __restrict__ cosT, float* __restrict__ sinT)
{
    int id = blockIdx.x * 256 + threadIdx.x;       // [0, 131072)
    int j = id & 15;
    int n = (id >> 4) & 7;
    int h = (id >> 7) & 511;
    int b = id >> 16;
    const float* pp = pos + (size_t)(b*DH + h)*4;
    float p = pp[0]*rope_w[0] + pp[1]*rope_w[1] + pp[2]*rope_w[2] + pp[3]*rope_w[3] + rope_b[0];
    int fi = n*HALFD + j;
    float freq = expf(-12.0f + (float)fi * (12.0f/127.0f));
    float ang = p * freq;                           // P_SCALE = 1
    cosT[id] = cosf(ang);
    sinT[id] = sinf(ang);
}

// ---------------------------------------------------------------------------
// Kernel 1: QG|K|V projection.  X(65536x256) @ W(256x1024) -> bf16 QGKV
//   cols: [0,256)=q  [256,512)=gate  [512,768)=k  [768,1024)=v
// Tiled 64x64, BK=16, 256 threads, 4x4 per thread, fp32 accumulate.
// ---------------------------------------------------------------------------
__global__ void __launch_bounds__(256) proj_kernel(
    const float* __restrict__ x,
    const float* __restrict__ Wq, const float* __restrict__ Wk, const float* __restrict__ Wv,
    u16* __restrict__ QGKV)
{
    __shared__ float As[16][64];   // [k][m]
    __shared__ float Bs[16][64];   // [k][n]
    int tid = threadIdx.x;
    int t0  = blockIdx.x * 64;     // token tile
    int n0g = blockIdx.y * 64;     // output-col tile (global, 0..960)

    const float* Wsel; int ldw, ncol;
    if (n0g < 512)      { Wsel = Wq; ldw = 512; ncol = n0g;       }
    else if (n0g < 768) { Wsel = Wk; ldw = 256; ncol = n0g - 512; }
    else                { Wsel = Wv; ldw = 256; ncol = n0g - 768; }

    int ar = tid >> 2;             // A row 0..63
    int ak = (tid & 3) * 4;        // A k   0,4,8,12
    int t  = t0 + ar;
    int bw = t >> 9, h = t & 511;
    int b  = bw >> 6, w = bw & 63;
    const float* arow = x + ((size_t)((b*DH + h)*DW + w))*DC;

    int br = tid >> 4;             // B k row 0..15
    int bc = (tid & 15) * 4;       // B col 0..60

    int m0 = (tid & 15) * 4;
    int n0 = (tid >> 4) * 4;
    float acc[4][4] = {};

    for (int k0 = 0; k0 < 256; k0 += 16) {
        float4 av = *reinterpret_cast<const float4*>(arow + k0 + ak);
        float4 bv = *reinterpret_cast<const float4*>(Wsel + (size_t)(k0 + br)*ldw + ncol + bc);
        __syncthreads();
        As[ak+0][ar] = av.x; As[ak+1][ar] = av.y; As[ak+2][ar] = av.z; As[ak+3][ar] = av.w;
        *reinterpret_cast<float4*>(&Bs[br][bc]) = bv;
        __syncthreads();
        #pragma unroll
        for (int k = 0; k < 16; ++k) {
            float a0 = As[k][m0+0], a1 = As[k][m0+1], a2 = As[k][m0+2], a3 = As[k][m0+3];
            float b0 = Bs[k][n0+0], b1 = Bs[k][n0+1], b2 = Bs[k][n0+2], b3 = Bs[k][n0+3];
            acc[0][0] += a0*b0; acc[0][1] += a0*b1; acc[0][2] += a0*b2; acc[0][3] += a0*b3;
            acc[1][0] += a1*b0; acc[1][1] += a1*b1; acc[1][2] += a1*b2; acc[1][3] += a1*b3;
            acc[2][0] += a2*b0; acc[2][1] += a2*b1; acc[2][2] += a2*b2; acc[2][3] += a2*b3;
            acc[3][0] += a3*b0; acc[3][1] += a3*b1; acc[3][2] += a3*b2; acc[3][3] += a3*b3;
        }
    }
    #pragma unroll
    for (int i = 0; i < 4; ++i) {
        int tt = t0 + m0 + i;
        ushort4 sv;
        sv.x = f2bf(acc[i][0]); sv.y = f2bf(acc[i][1]);
        sv.z = f2bf(acc[i][2]); sv.w = f2bf(acc[i][3]);
        *reinterpret_cast<ushort4*>(QGKV + (size_t)tt*1024 + n0g + n0) = sv;
    }
}

// ---------------------------------------------------------------------------
// Kernel 2: RMSNorm(hd=32) + RoPE on q and k, in place (bf16 -> bf16).
// One thread per (t, which in {q,k}, head n).
// ---------------------------------------------------------------------------
__global__ void __launch_bounds__(256) normrope_kernel(
    u16* __restrict__ QGKV,
    const float* __restrict__ q_norm_w, const float* __restrict__ k_norm_w,
    const float* __restrict__ cosT, const float* __restrict__ sinT)
{
    int id = blockIdx.x * 256 + threadIdx.x;     // [0, 1048576)
    int n     = id & 7;
    int which = (id >> 3) & 1;                   // 0=q, 1=k
    int t     = id >> 4;
    int col   = (which ? 512 : 0) + n*HDIM;
    u16* ptr  = QGKV + (size_t)t*1024 + col;

    u32 raw[16];
    const uint4* p4 = reinterpret_cast<const uint4*>(ptr);
    #pragma unroll
    for (int i = 0; i < 4; ++i) {
        uint4 r = p4[i];
        raw[4*i+0] = r.x; raw[4*i+1] = r.y; raw[4*i+2] = r.z; raw[4*i+3] = r.w;
    }
    float v[32];
    float ss = 0.f;
    #pragma unroll
    for (int i = 0; i < 16; ++i) {
        v[2*i]   = bf_lo(raw[i]);
        v[2*i+1] = bf_hi(raw[i]);
        ss += v[2*i]*v[2*i] + v[2*i+1]*v[2*i+1];
    }
    float rs = rsqrtf(ss * (1.0f/32.0f) + 1e-6f);
    const float* nw = which ? k_norm_w : q_norm_w;
    #pragma unroll
    for (int d = 0; d < 32; ++d) v[d] *= rs * nw[d];

    int bw = t >> 9, h = t & 511, b = bw >> 6;
    int tb = ((b*DH + h)*NHEADS + n)*HALFD;
    #pragma unroll
    for (int j = 0; j < 16; ++j) {
        float c = cosT[tb + j], s = sinT[tb + j];
        float e = v[2*j], o = v[2*j+1];
        v[2*j]   = e*c - o*s;
        v[2*j+1] = e*s + o*c;
    }
    uint4* w4 = reinterpret_cast<uint4*>(ptr);
    #pragma unroll
    for (int i = 0; i < 4; ++i) {
        uint4 r;
        r.x = (u32)f2bf(v[8*i+0]) | ((u32)f2bf(v[8*i+1]) << 16);
        r.y = (u32)f2bf(v[8*i+2]) | ((u32)f2bf(v[8*i+3]) << 16);
        r.z = (u32)f2bf(v[8*i+4]) | ((u32)f2bf(v[8*i+5]) << 16);
        r.w = (u32)f2bf(v[8*i+6]) | ((u32)f2bf(v[8*i+7]) << 16);
        w4[i] = r;
    }
}

// ---------------------------------------------------------------------------
// Kernel 3: attention per (bw, head).  S=512, D=32, online softmax.
// 512 threads = 1 query row each; K,V staged bf16 in LDS (64 KiB).
// Output: o*sigmoid(gate), bf16, overwrites q columns (AG buffer).
// ---------------------------------------------------------------------------
__global__ void __launch_bounds__(512) attn_kernel(u16* __restrict__ QGKV)
{
    __shared__ u16 Kl[512*HDIM];
    __shared__ u16 Vl[512*HDIM];
    int bid = blockIdx.x;                 // [0,1024)
    int bw = bid >> 3, n = bid & 7;
    int tid = threadIdx.x;                // query row h
    size_t tbase = ((size_t)(bw*DH + tid))*1024;

    const uint4* kg = reinterpret_cast<const uint4*>(QGKV + tbase + 512 + n*HDIM);
    const uint4* vg = reinterpret_cast<const uint4*>(QGKV + tbase + 768 + n*HDIM);
    uint4* kls = reinterpret_cast<uint4*>(Kl + tid*HDIM);
    uint4* vls = reinterpret_cast<uint4*>(Vl + tid*HDIM);
    #pragma unroll
    for (int i = 0; i < 4; ++i) { kls[i] = kg[i]; vls[i] = vg[i]; }

    float q[32];
    {
        const uint4* qg4 = reinterpret_cast<const uint4*>(QGKV + tbase + n*HDIM);
        #pragma unroll
        for (int i = 0; i < 4; ++i) {
            uint4 r = qg4[i];
            u32 rw[4] = {r.x, r.y, r.z, r.w};
            #pragma unroll
            for (int kk = 0; kk < 4; ++kk) {
                q[8*i+2*kk]   = bf_lo(rw[kk]);
                q[8*i+2*kk+1] = bf_hi(rw[kk]);
            }
        }
    }
    __syncthreads();

    float o[32];
    #pragma unroll
    for (int d = 0; d < 32; ++d) o[d] = 0.f;
    float m = -3.0e38f, l = 0.f;

    for (int j = 0; j < 512; ++j) {
        const uint4* kr = reinterpret_cast<const uint4*>(Kl + j*HDIM);
        float s = 0.f;
        #pragma unroll
        for (int i = 0; i < 4; ++i) {
            uint4 r = kr[i];
            u32 rw[4] = {r.x, r.y, r.z, r.w};
            #pragma unroll
            for (int kk = 0; kk < 4; ++kk) {
                s += q[8*i+2*kk]*bf_lo(rw[kk]) + q[8*i+2*kk+1]*bf_hi(rw[kk]);
            }
        }
        s *= 0.17677669529663687f;        // 32^-0.5
        float p;
        if (s > m) {                      // rescale path (rare after warm-up)
            float corr = __expf(m - s);
            l *= corr;
            #pragma unroll
            for (int d = 0; d < 32; ++d) o[d] *= corr;
            m = s;
            p = 1.0f;
        } else {
            p = __expf(s - m);
        }
        l += p;
        const uint4* vr = reinterpret_cast<const uint4*>(Vl + j*HDIM);
        #pragma unroll
        for (int i = 0; i < 4; ++i) {
            uint4 r = vr[i];
            u32 rw[4] = {r.x, r.y, r.z, r.w};
            #pragma unroll
            for (int kk = 0; kk < 4; ++kk) {
                o[8*i+2*kk]   += p*bf_lo(rw[kk]);
                o[8*i+2*kk+1] += p*bf_hi(rw[kk]);
            }
        }
    }
    float inv = 1.0f / l;

    const uint4* gg = reinterpret_cast<const uint4*>(QGKV + tbase + 256 + n*HDIM);
    uint4 wout[4];
    #pragma unroll
    for (int i = 0; i < 4; ++i) {
        uint4 r = gg[i];
        u32 rw[4] = {r.x, r.y, r.z, r.w};
        u32 pk[4];
        #pragma unroll
        for (int kk = 0; kk < 4; ++kk) {
            float glo = bf_lo(rw[kk]), ghi = bf_hi(rw[kk]);
            float rlo = o[8*i+2*kk]  *inv * (1.f/(1.f + __expf(-glo)));
            float rhi = o[8*i+2*kk+1]*inv * (1.f/(1.f + __expf(-ghi)));
            pk[kk] = (u32)f2bf(rlo) | ((u32)f2bf(rhi) << 16);
        }
        wout[i] = make_uint4(pk[0], pk[1], pk[2], pk[3]);
    }
    uint4* od = reinterpret_cast<uint4*>(QGKV + tbase + n*HDIM);
    #pragma unroll
    for (int i = 0; i < 4; ++i) od[i] = wout[i];
}

// ---------------------------------------------------------------------------
// Kernel 4: output projection. AG(65536x256 bf16, ld=1024) @ Wo + bo -> out
// scattered to (B,H,W,C) fp32.
// ---------------------------------------------------------------------------
__global__ void __launch_bounds__(256) outproj_kernel(
    const u16* __restrict__ QGKV,
    const float* __restrict__ Wo, const float* __restrict__ bo,
    float* __restrict__ out)
{
    __shared__ float As[16][64];
    __shared__ float Bs[16][64];
    int tid = threadIdx.x;
    int t0    = blockIdx.x * 64;
    int nbase = blockIdx.y * 64;

    int ar = tid >> 2;
    int ak = (tid & 3) * 4;
    const u16* arow = QGKV + (size_t)(t0 + ar)*1024;

    int br = tid >> 4;
    int bc = (tid & 15) * 4;
    int m0 = (tid & 15) * 4;
    int n0 = (tid >> 4) * 4;
    float acc[4][4] = {};

    for (int k0 = 0; k0 < 256; k0 += 16) {
        ushort4 av = *reinterpret_cast<const ushort4*>(arow + k0 + ak);
        float4  bv = *reinterpret_cast<const float4*>(Wo + (size_t)(k0 + br)*DC + nbase + bc);
        __syncthreads();
        As[ak+0][ar] = bfu(av.x); As[ak+1][ar] = bfu(av.y);
        As[ak+2][ar] = bfu(av.z); As[ak+3][ar] = bfu(av.w);
        *reinterpret_cast<float4*>(&Bs[br][bc]) = bv;
        __syncthreads();
        #pragma unroll
        for (int k = 0; k < 16; ++k) {
            float a0 = As[k][m0+0], a1 = As[k][m0+1], a2 = As[k][m0+2], a3 = As[k][m0+3];
            float b0 = Bs[k][n0+0], b1 = Bs[k][n0+1], b2 = Bs[k][n0+2], b3 = Bs[k][n0+3];
            acc[0][0] += a0*b0; acc[0][1] += a0*b1; acc[0][2] += a0*b2; acc[0][3] += a0*b3;
            acc[1][0] += a1*b0; acc[1][1] += a1*b1; acc[1][2] += a1*b2; acc[1][3] += a1*b3;
            acc[2][0] += a2*b0; acc[2][1] += a2*b1; acc[2][2] += a2*b2; acc[2][3] += a2*b3;
            acc[3][0] += a3*b0; acc[3][1] += a3*b1; acc[3][2] += a3*b2; acc[3][3] += a3*b3;
        }
    }
    #pragma unroll
    for (int i = 0; i < 4; ++i) {
        int t = t0 + m0 + i;
        int bw = t >> 9, h = t & 511, b = bw >> 6, w = bw & 63;
        float4 res;
        res.x = acc[i][0] + bo[nbase+n0+0];
        res.y = acc[i][1] + bo[nbase+n0+1];
        res.z = acc[i][2] + bo[nbase+n0+2];
        res.w = acc[i][3] + bo[nbase+n0+3];
        *reinterpret_cast<float4*>(out + ((size_t)((b*DH + h)*DW + w))*DC + nbase + n0) = res;
    }
}

// ---------------------------------------------------------------------------
extern "C" void kernel_launch(void* const* d_in, const int* in_sizes, int n_in,
                              void* d_out, int out_size, void* d_ws, size_t ws_size,
                              hipStream_t stream)
{
    const float* x      = (const float*)d_in[0];
    const float* pos    = (const float*)d_in[1];
    const float* Wq     = (const float*)d_in[2];
    const float* Wk     = (const float*)d_in[3];
    const float* Wv     = (const float*)d_in[4];
    const float* Wo     = (const float*)d_in[5];
    const float* bo     = (const float*)d_in[6];
    const float* qnw    = (const float*)d_in[7];
    const float* knw    = (const float*)d_in[8];
    const float* rope_w = (const float*)d_in[9];
    const float* rope_b = (const float*)d_in[10];
    float* out = (float*)d_out;

    u16*   QGKV = (u16*)d_ws;                                     // 65536 x 1024 bf16 = 128 MiB
    float* cosT = (float*)((char*)d_ws + (size_t)NTOK*1024*2);    // 131072 f32
    float* sinT = cosT + DB*DH*NHEADS*HALFD;                      // 131072 f32

    rope_table_kernel<<<dim3(512),      dim3(256), 0, stream>>>(pos, rope_w, rope_b, cosT, sinT);
    proj_kernel      <<<dim3(1024, 16), dim3(256), 0, stream>>>(x, Wq, Wk, Wv, QGKV);
    normrope_kernel  <<<dim3(4096),     dim3(256), 0, stream>>>(QGKV, qnw, knw, cosT, sinT);
    attn_kernel      <<<dim3(1024),     dim3(512), 0, stream>>>(QGKV);
    outproj_kernel   <<<dim3(1024, 4),  dim3(256), 0, stream>>>(QGKV, Wo, bo, out);
}

// Round 2
// 713.024 us; speedup vs baseline: 2.4129x; 2.4129x over previous
//
#include <hip/hip_runtime.h>
#include <hip/hip_bf16.h>
#include <math.h>

#define NHEADS 8
#define HDIM   32
#define HALFD  16
#define DB     2
#define DH     512
#define DW     64
#define DC     256
#define NTOK   (DB*DW*DH)   /* 65536 tokens, t = (b*64+w)*512 + h */

typedef unsigned short u16;
typedef unsigned int   u32;
typedef short short8 __attribute__((ext_vector_type(8)));
typedef float f32x4  __attribute__((ext_vector_type(4)));

__device__ __forceinline__ float bf_lo(u32 u){ union{u32 i; float f;} c; c.i = u << 16; return c.f; }
__device__ __forceinline__ float bf_hi(u32 u){ union{u32 i; float f;} c; c.i = u & 0xffff0000u; return c.f; }
__device__ __forceinline__ float bfu(u16 u){ union{u32 i; float f;} c; c.i = ((u32)u) << 16; return c.f; }
__device__ __forceinline__ u16 f2bf(float f){
    u32 x = __float_as_uint(f);
    u32 r = (x + 0x7fffu + ((x >> 16) & 1u)) >> 16;   // RTN-even
    return (u16)r;
}
// fast pack: round-to-nearest (ties up) bf16 pair -> u32
__device__ __forceinline__ u32 pack_bf2(float a, float b){
    u32 ua = (__float_as_uint(a) + 0x8000u) >> 16;
    u32 ub = (__float_as_uint(b) + 0x8000u) & 0xffff0000u;
    return ua | ub;
}
__device__ __forceinline__ u16 f2bf_fast(float f){
    return (u16)((__float_as_uint(f) + 0x8000u) >> 16);
}

// ---------------------------------------------------------------------------
// Kernel 0: cos/sin table  [b][h][n][j]  (131072 entries each)
// ---------------------------------------------------------------------------
__global__ void __launch_bounds__(256) rope_table_kernel(
    const float* __restrict__ pos, const float* __restrict__ rope_w,
    const float* __restrict__ rope_b, float* __restrict__ cosT, float* __restrict__ sinT)
{
    int id = blockIdx.x * 256 + threadIdx.x;       // [0, 131072)
    int j = id & 15;
    int n = (id >> 4) & 7;
    int h = (id >> 7) & 511;
    int b = id >> 16;
    const float* pp = pos + (size_t)(b*DH + h)*4;
    float p = pp[0]*rope_w[0] + pp[1]*rope_w[1] + pp[2]*rope_w[2] + pp[3]*rope_w[3] + rope_b[0];
    int fi = n*HALFD + j;
    float freq = expf(-12.0f + (float)fi * (12.0f/127.0f));
    float ang = p * freq;                           // P_SCALE = 1
    cosT[id] = cosf(ang);
    sinT[id] = sinf(ang);
}

// ---------------------------------------------------------------------------
// Kernel 1: QG|K|V projection.  X(65536x256) @ W(256x1024) -> bf16 QGKV
//   cols: [0,256)=q  [256,512)=gate  [512,768)=k  [768,1024)=v
// ---------------------------------------------------------------------------
__global__ void __launch_bounds__(256) proj_kernel(
    const float* __restrict__ x,
    const float* __restrict__ Wq, const float* __restrict__ Wk, const float* __restrict__ Wv,
    u16* __restrict__ QGKV)
{
    __shared__ float As[16][64];   // [k][m]
    __shared__ float Bs[16][64];   // [k][n]
    int tid = threadIdx.x;
    int t0  = blockIdx.x * 64;     // token tile
    int n0g = blockIdx.y * 64;     // output-col tile (global, 0..960)

    const float* Wsel; int ldw, ncol;
    if (n0g < 512)      { Wsel = Wq; ldw = 512; ncol = n0g;       }
    else if (n0g < 768) { Wsel = Wk; ldw = 256; ncol = n0g - 512; }
    else                { Wsel = Wv; ldw = 256; ncol = n0g - 768; }

    int ar = tid >> 2;             // A row 0..63
    int ak = (tid & 3) * 4;        // A k   0,4,8,12
    int t  = t0 + ar;
    int bw = t >> 9, h = t & 511;
    int b  = bw >> 6, w = bw & 63;
    const float* arow = x + ((size_t)((b*DH + h)*DW + w))*DC;

    int br = tid >> 4;             // B k row 0..15
    int bc = (tid & 15) * 4;       // B col 0..60

    int m0 = (tid & 15) * 4;
    int n0 = (tid >> 4) * 4;
    float acc[4][4] = {};

    for (int k0 = 0; k0 < 256; k0 += 16) {
        float4 av = *reinterpret_cast<const float4*>(arow + k0 + ak);
        float4 bv = *reinterpret_cast<const float4*>(Wsel + (size_t)(k0 + br)*ldw + ncol + bc);
        __syncthreads();
        As[ak+0][ar] = av.x; As[ak+1][ar] = av.y; As[ak+2][ar] = av.z; As[ak+3][ar] = av.w;
        *reinterpret_cast<float4*>(&Bs[br][bc]) = bv;
        __syncthreads();
        #pragma unroll
        for (int k = 0; k < 16; ++k) {
            float a0 = As[k][m0+0], a1 = As[k][m0+1], a2 = As[k][m0+2], a3 = As[k][m0+3];
            float b0 = Bs[k][n0+0], b1 = Bs[k][n0+1], b2 = Bs[k][n0+2], b3 = Bs[k][n0+3];
            acc[0][0] += a0*b0; acc[0][1] += a0*b1; acc[0][2] += a0*b2; acc[0][3] += a0*b3;
            acc[1][0] += a1*b0; acc[1][1] += a1*b1; acc[1][2] += a1*b2; acc[1][3] += a1*b3;
            acc[2][0] += a2*b0; acc[2][1] += a2*b1; acc[2][2] += a2*b2; acc[2][3] += a2*b3;
            acc[3][0] += a3*b0; acc[3][1] += a3*b1; acc[3][2] += a3*b2; acc[3][3] += a3*b3;
        }
    }
    #pragma unroll
    for (int i = 0; i < 4; ++i) {
        int tt = t0 + m0 + i;
        ushort4 sv;
        sv.x = f2bf(acc[i][0]); sv.y = f2bf(acc[i][1]);
        sv.z = f2bf(acc[i][2]); sv.w = f2bf(acc[i][3]);
        *reinterpret_cast<ushort4*>(QGKV + (size_t)tt*1024 + n0g + n0) = sv;
    }
}

// ---------------------------------------------------------------------------
// Kernel 2: RMSNorm(hd=32) + RoPE on q and k, in place (bf16 -> bf16).
// ---------------------------------------------------------------------------
__global__ void __launch_bounds__(256) normrope_kernel(
    u16* __restrict__ QGKV,
    const float* __restrict__ q_norm_w, const float* __restrict__ k_norm_w,
    const float* __restrict__ cosT, const float* __restrict__ sinT)
{
    int id = blockIdx.x * 256 + threadIdx.x;     // [0, 1048576)
    int n     = id & 7;
    int which = (id >> 3) & 1;                   // 0=q, 1=k
    int t     = id >> 4;
    int col   = (which ? 512 : 0) + n*HDIM;
    u16* ptr  = QGKV + (size_t)t*1024 + col;

    u32 raw[16];
    const uint4* p4 = reinterpret_cast<const uint4*>(ptr);
    #pragma unroll
    for (int i = 0; i < 4; ++i) {
        uint4 r = p4[i];
        raw[4*i+0] = r.x; raw[4*i+1] = r.y; raw[4*i+2] = r.z; raw[4*i+3] = r.w;
    }
    float v[32];
    float ss = 0.f;
    #pragma unroll
    for (int i = 0; i < 16; ++i) {
        v[2*i]   = bf_lo(raw[i]);
        v[2*i+1] = bf_hi(raw[i]);
        ss += v[2*i]*v[2*i] + v[2*i+1]*v[2*i+1];
    }
    float rs = rsqrtf(ss * (1.0f/32.0f) + 1e-6f);
    const float* nw = which ? k_norm_w : q_norm_w;
    #pragma unroll
    for (int d = 0; d < 32; ++d) v[d] *= rs * nw[d];

    int bw = t >> 9, h = t & 511, b = bw >> 6;
    int tb = ((b*DH + h)*NHEADS + n)*HALFD;
    #pragma unroll
    for (int j = 0; j < 16; ++j) {
        float c = cosT[tb + j], s = sinT[tb + j];
        float e = v[2*j], o = v[2*j+1];
        v[2*j]   = e*c - o*s;
        v[2*j+1] = e*s + o*c;
    }
    uint4* w4 = reinterpret_cast<uint4*>(ptr);
    #pragma unroll
    for (int i = 0; i < 4; ++i) {
        uint4 r;
        r.x = (u32)f2bf(v[8*i+0]) | ((u32)f2bf(v[8*i+1]) << 16);
        r.y = (u32)f2bf(v[8*i+2]) | ((u32)f2bf(v[8*i+3]) << 16);
        r.z = (u32)f2bf(v[8*i+4]) | ((u32)f2bf(v[8*i+5]) << 16);
        r.w = (u32)f2bf(v[8*i+6]) | ((u32)f2bf(v[8*i+7]) << 16);
        w4[i] = r;
    }
}

// ---------------------------------------------------------------------------
// Kernel 3: MFMA flash attention per (bw, head).  S=512, D=32.
// 8 waves x 64 q-rows. Swapped QK^T (A=K, B=Q) -> q = lane&15 everywhere.
// K frag-linear in LDS, V^T frag-linear in LDS, per-wave XOR-swizzled P.
// Output: o*sigmoid(gate), bf16, overwrites q columns.
// ---------------------------------------------------------------------------
__global__ void __launch_bounds__(512) attn_kernel(u16* __restrict__ QGKV)
{
    // K frag-linear: per 16-key tile kt16: 4 g-blocks x 16 rows x 16B
    //   u16 idx = kt16*512 + g*128 + (key&15)*8 + j
    __shared__ u16 KL[512*32];       // 32 KiB
    // V^T frag-linear: per 32-key step st: [df][g][lq] 16B blocks
    //   u16 idx = st*1024 + df*512 + (g*16+lq)*8 + j   (holds V[key][16df+lq])
    __shared__ u16 VT[32*512];       // 32 KiB
    // P scratch per wave: [64 q][8 kb x 8] with kb ^= (q&7)
    __shared__ u16 PL[8*64*64];      // 64 KiB

    int bid  = blockIdx.x;           // [0,1024)
    int bw   = bid >> 3, n = bid & 7;
    int tid  = threadIdx.x;
    int lane = tid & 63;
    int wv   = tid >> 6;
    int g    = lane >> 4;            // 0..3
    int lq   = lane & 15;

    // ---- stage K and V^T (all 512 threads, one key row each) ----
    {
        int i = tid;
        size_t tb = ((size_t)(bw*DH + i))*1024;
        const uint4* ks = reinterpret_cast<const uint4*>(QGKV + tb + 512 + n*HDIM);
        #pragma unroll
        for (int gg = 0; gg < 4; ++gg) {
            *reinterpret_cast<uint4*>(KL + (i>>4)*512 + gg*128 + (i&15)*8) = ks[gg];
        }
        const uint4* vsrc = reinterpret_cast<const uint4*>(QGKV + tb + 768 + n*HDIM);
        uint4 vv[4];
        #pragma unroll
        for (int gg = 0; gg < 4; ++gg) vv[gg] = vsrc[gg];
        const u16* vp = reinterpret_cast<const u16*>(vv);
        int st = i >> 5, vg = (i >> 3) & 3, vj = i & 7;
        #pragma unroll
        for (int d = 0; d < 32; ++d) {
            VT[st*1024 + (d>>4)*512 + vg*128 + (d&15)*8 + vj] = vp[d];
        }
    }

    // ---- load Q fragments (B-operand: lane holds Q[q=lq][k=g*8..+7]) ----
    short8 qf[4];
    #pragma unroll
    for (int qt = 0; qt < 4; ++qt) {
        int t = bw*DH + wv*64 + qt*16 + lq;
        union { uint4 u; short8 s; } c;
        c.u = *reinterpret_cast<const uint4*>(QGKV + (size_t)t*1024 + n*HDIM + g*8);
        qf[qt] = c.s;
    }
    __syncthreads();

    f32x4 oacc[4][2];
    float m_run[4], l_run[4];
    #pragma unroll
    for (int qt = 0; qt < 4; ++qt) {
        oacc[qt][0] = (f32x4){0.f,0.f,0.f,0.f};
        oacc[qt][1] = (f32x4){0.f,0.f,0.f,0.f};
        m_run[qt] = -3.0e38f;
        l_run[qt] = 0.f;
    }

    u16* PW = PL + wv*4096;
    const float CSC = 0.17677669529663687f * 1.4426950408889634f;  // scale*log2e
    const int qx = lq & 7;

    for (int kt64 = 0; kt64 < 8; ++kt64) {
        // K A-frags: lane-linear reads
        short8 kf[4];
        #pragma unroll
        for (int kt = 0; kt < 4; ++kt) {
            union { uint4 u; short8 s; } c;
            c.u = *reinterpret_cast<const uint4*>(KL + (kt64*4 + kt)*512 + lane*8);
            kf[kt] = c.s;
        }
        // ---- QK^T + online softmax per q-frag ----
        #pragma unroll
        for (int qt = 0; qt < 4; ++qt) {
            f32x4 sf[4];
            #pragma unroll
            for (int kt = 0; kt < 4; ++kt)
                sf[kt] = __builtin_amdgcn_mfma_f32_16x16x32_bf16(
                    kf[kt], qf[qt], (f32x4){0.f,0.f,0.f,0.f}, 0, 0, 0);
            float z[16];
            float tmax = -3.0e38f;
            #pragma unroll
            for (int kt = 0; kt < 4; ++kt) {
                #pragma unroll
                for (int r = 0; r < 4; ++r) {
                    float zz = sf[kt][r] * CSC;
                    z[kt*4+r] = zz;
                    tmax = fmaxf(tmax, zz);
                }
            }
            tmax = fmaxf(tmax, __shfl_xor(tmax, 16));
            tmax = fmaxf(tmax, __shfl_xor(tmax, 32));
            float mo = m_run[qt];
            float mn = fmaxf(mo, tmax);
            float corr = __builtin_amdgcn_exp2f(mo - mn);
            m_run[qt] = mn;
            l_run[qt] *= corr;
            oacc[qt][0] *= corr;
            oacc[qt][1] *= corr;
            float p[16];
            float ls = 0.f;
            #pragma unroll
            for (int i = 0; i < 16; ++i) {
                float pv = __builtin_amdgcn_exp2f(z[i] - mn);
                p[i] = pv; ls += pv;
            }
            l_run[qt] += ls;
            // write P (bf16) to per-wave swizzled scratch
            int qrow = (qt*16 + lq)*64;
            #pragma unroll
            for (int kt = 0; kt < 4; ++kt) {
                int kb = 2*kt + (g>>1);
                int base = qrow + ((kb ^ qx)*8) + 4*(g&1);
                *reinterpret_cast<u32*>(PW + base)     = pack_bf2(p[kt*4+0], p[kt*4+1]);
                *reinterpret_cast<u32*>(PW + base + 2) = pack_bf2(p[kt*4+2], p[kt*4+3]);
            }
        }
        // ---- PV: O^T += V^T . P^T ----
        #pragma unroll
        for (int ks = 0; ks < 2; ++ks) {
            short8 va[2];
            #pragma unroll
            for (int df = 0; df < 2; ++df) {
                union { uint4 u; short8 s; } c;
                c.u = *reinterpret_cast<const uint4*>(VT + (kt64*2 + ks)*1024 + df*512 + lane*8);
                va[df] = c.s;
            }
            short8 pb[4];
            #pragma unroll
            for (int qt = 0; qt < 4; ++qt) {
                union { uint4 u; short8 s; } c;
                c.u = *reinterpret_cast<const uint4*>(PW + (qt*16 + lq)*64 + (((4*ks + g) ^ qx)*8));
                pb[qt] = c.s;
            }
            #pragma unroll
            for (int qt = 0; qt < 4; ++qt) {
                oacc[qt][0] = __builtin_amdgcn_mfma_f32_16x16x32_bf16(va[0], pb[qt], oacc[qt][0], 0, 0, 0);
                oacc[qt][1] = __builtin_amdgcn_mfma_f32_16x16x32_bf16(va[1], pb[qt], oacc[qt][1], 0, 0, 0);
            }
        }
    }

    // ---- epilogue: normalize, gate, store (overwrites q columns) ----
    #pragma unroll
    for (int qt = 0; qt < 4; ++qt) {
        float lr = l_run[qt];
        lr += __shfl_xor(lr, 16);
        lr += __shfl_xor(lr, 32);
        float inv = 1.0f / lr;
        int t = bw*DH + wv*64 + qt*16 + lq;
        size_t tb = (size_t)t*1024;
        #pragma unroll
        for (int df = 0; df < 2; ++df) {
            int col = n*HDIM + 16*df + 4*g;
            ushort4 gv = *reinterpret_cast<const ushort4*>(QGKV + tb + 256 + col);
            u16 gr[4] = {gv.x, gv.y, gv.z, gv.w};
            ushort4 ov;
            u16 orr[4];
            #pragma unroll
            for (int r = 0; r < 4; ++r) {
                float o  = oacc[qt][df][r] * inv;
                float gf = bfu(gr[r]);
                float sg = 1.0f / (1.0f + __builtin_amdgcn_exp2f(-gf * 1.4426950408889634f));
                orr[r] = f2bf_fast(o * sg);
            }
            ov.x = orr[0]; ov.y = orr[1]; ov.z = orr[2]; ov.w = orr[3];
            *reinterpret_cast<ushort4*>(QGKV + tb + col) = ov;
        }
    }
}

// ---------------------------------------------------------------------------
// Kernel 4: output projection. AG(65536x256 bf16, ld=1024) @ Wo + bo -> out
// ---------------------------------------------------------------------------
__global__ void __launch_bounds__(256) outproj_kernel(
    const u16* __restrict__ QGKV,
    const float* __restrict__ Wo, const float* __restrict__ bo,
    float* __restrict__ out)
{
    __shared__ float As[16][64];
    __shared__ float Bs[16][64];
    int tid = threadIdx.x;
    int t0    = blockIdx.x * 64;
    int nbase = blockIdx.y * 64;

    int ar = tid >> 2;
    int ak = (tid & 3) * 4;
    const u16* arow = QGKV + (size_t)(t0 + ar)*1024;

    int br = tid >> 4;
    int bc = (tid & 15) * 4;
    int m0 = (tid & 15) * 4;
    int n0 = (tid >> 4) * 4;
    float acc[4][4] = {};

    for (int k0 = 0; k0 < 256; k0 += 16) {
        ushort4 av = *reinterpret_cast<const ushort4*>(arow + k0 + ak);
        float4  bv = *reinterpret_cast<const float4*>(Wo + (size_t)(k0 + br)*DC + nbase + bc);
        __syncthreads();
        As[ak+0][ar] = bfu(av.x); As[ak+1][ar] = bfu(av.y);
        As[ak+2][ar] = bfu(av.z); As[ak+3][ar] = bfu(av.w);
        *reinterpret_cast<float4*>(&Bs[br][bc]) = bv;
        __syncthreads();
        #pragma unroll
        for (int k = 0; k < 16; ++k) {
            float a0 = As[k][m0+0], a1 = As[k][m0+1], a2 = As[k][m0+2], a3 = As[k][m0+3];
            float b0 = Bs[k][n0+0], b1 = Bs[k][n0+1], b2 = Bs[k][n0+2], b3 = Bs[k][n0+3];
            acc[0][0] += a0*b0; acc[0][1] += a0*b1; acc[0][2] += a0*b2; acc[0][3] += a0*b3;
            acc[1][0] += a1*b0; acc[1][1] += a1*b1; acc[1][2] += a1*b2; acc[1][3] += a1*b3;
            acc[2][0] += a2*b0; acc[2][1] += a2*b1; acc[2][2] += a2*b2; acc[2][3] += a2*b3;
            acc[3][0] += a3*b0; acc[3][1] += a3*b1; acc[3][2] += a3*b2; acc[3][3] += a3*b3;
        }
    }
    #pragma unroll
    for (int i = 0; i < 4; ++i) {
        int t = t0 + m0 + i;
        int bw = t >> 9, h = t & 511, b = bw >> 6, w = bw & 63;
        float4 res;
        res.x = acc[i][0] + bo[nbase+n0+0];
        res.y = acc[i][1] + bo[nbase+n0+1];
        res.z = acc[i][2] + bo[nbase+n0+2];
        res.w = acc[i][3] + bo[nbase+n0+3];
        *reinterpret_cast<float4*>(out + ((size_t)((b*DH + h)*DW + w))*DC + nbase + n0) = res;
    }
}

// ---------------------------------------------------------------------------
extern "C" void kernel_launch(void* const* d_in, const int* in_sizes, int n_in,
                              void* d_out, int out_size, void* d_ws, size_t ws_size,
                              hipStream_t stream)
{
    const float* x      = (const float*)d_in[0];
    const float* pos    = (const float*)d_in[1];
    const float* Wq     = (const float*)d_in[2];
    const float* Wk     = (const float*)d_in[3];
    const float* Wv     = (const float*)d_in[4];
    const float* Wo     = (const float*)d_in[5];
    const float* bo     = (const float*)d_in[6];
    const float* qnw    = (const float*)d_in[7];
    const float* knw    = (const float*)d_in[8];
    const float* rope_w = (const float*)d_in[9];
    const float* rope_b = (const float*)d_in[10];
    float* out = (float*)d_out;

    u16*   QGKV = (u16*)d_ws;                                     // 65536 x 1024 bf16 = 128 MiB
    float* cosT = (float*)((char*)d_ws + (size_t)NTOK*1024*2);    // 131072 f32
    float* sinT = cosT + DB*DH*NHEADS*HALFD;                      // 131072 f32

    rope_table_kernel<<<dim3(512),      dim3(256), 0, stream>>>(pos, rope_w, rope_b, cosT, sinT);
    proj_kernel      <<<dim3(1024, 16), dim3(256), 0, stream>>>(x, Wq, Wk, Wv, QGKV);
    normrope_kernel  <<<dim3(4096),     dim3(256), 0, stream>>>(QGKV, qnw, knw, cosT, sinT);
    attn_kernel      <<<dim3(1024),     dim3(512), 0, stream>>>(QGKV);
    outproj_kernel   <<<dim3(1024, 4),  dim3(256), 0, stream>>>(QGKV, Wo, bo, out);
}

// Round 3
// 283.511 us; speedup vs baseline: 6.0683x; 2.5150x over previous
//
#include <hip/hip_runtime.h>
#include <hip/hip_bf16.h>
#include <math.h>

#define NHEADS 8
#define HDIM   32
#define HALFD  16
#define DB     2
#define DH     512
#define DW     64
#define DC     256
#define NTOK   (DB*DW*DH)   /* 65536 tokens, t = (b*64+w)*512 + h */

typedef unsigned short u16;
typedef unsigned int   u32;
typedef short short8 __attribute__((ext_vector_type(8)));
typedef float f32x4  __attribute__((ext_vector_type(4)));

__device__ __forceinline__ float bf_lo(u32 u){ union{u32 i; float f;} c; c.i = u << 16; return c.f; }
__device__ __forceinline__ float bf_hi(u32 u){ union{u32 i; float f;} c; c.i = u & 0xffff0000u; return c.f; }
__device__ __forceinline__ float bfu(u16 u){ union{u32 i; float f;} c; c.i = ((u32)u) << 16; return c.f; }
__device__ __forceinline__ u16 f2bf(float f){
    u32 x = __float_as_uint(f);
    u32 r = (x + 0x7fffu + ((x >> 16) & 1u)) >> 16;   // RTN-even
    return (u16)r;
}
// fast pack: round-to-nearest (ties up) bf16 pair -> u32
__device__ __forceinline__ u32 pack_bf2(float a, float b){
    u32 ua = (__float_as_uint(a) + 0x8000u) >> 16;
    u32 ub = (__float_as_uint(b) + 0x8000u) & 0xffff0000u;
    return ua | ub;
}
__device__ __forceinline__ u16 f2bf_fast(float f){
    return (u16)((__float_as_uint(f) + 0x8000u) >> 16);
}

// ---------------------------------------------------------------------------
// Kernel 0: cos/sin table  [b][h][n][j]  (131072 entries each)
// ---------------------------------------------------------------------------
__global__ void __launch_bounds__(256) rope_table_kernel(
    const float* __restrict__ pos, const float* __restrict__ rope_w,
    const float* __restrict__ rope_b, float* __restrict__ cosT, float* __restrict__ sinT)
{
    int id = blockIdx.x * 256 + threadIdx.x;       // [0, 131072)
    int j = id & 15;
    int n = (id >> 4) & 7;
    int h = (id >> 7) & 511;
    int b = id >> 16;
    const float* pp = pos + (size_t)(b*DH + h)*4;
    float p = pp[0]*rope_w[0] + pp[1]*rope_w[1] + pp[2]*rope_w[2] + pp[3]*rope_w[3] + rope_b[0];
    int fi = n*HALFD + j;
    float freq = expf(-12.0f + (float)fi * (12.0f/127.0f));
    float ang = p * freq;                           // P_SCALE = 1
    cosT[id] = cosf(ang);
    sinT[id] = sinf(ang);
}

// ---------------------------------------------------------------------------
// Kernel 0b: weight convert/transpose.
//   Wt [n=1024][k=256] bf16 : n<512 -> Wq[:,n]; n<768 -> Wk[:,n-512]; else Wv
//   Wot[n= 256][k=256] bf16 : Wo[:,n]
// ---------------------------------------------------------------------------
__global__ void __launch_bounds__(256) wconv_kernel(
    const float* __restrict__ Wq, const float* __restrict__ Wk,
    const float* __restrict__ Wv, const float* __restrict__ Wo,
    u16* __restrict__ Wt, u16* __restrict__ Wot)
{
    int eid = blockIdx.x*256 + threadIdx.x;        // [0, 40960)
    if (eid < 32768) {
        int nn = eid >> 5, k0 = (eid & 31)*8;
        const float* src; int ld, nl;
        if (nn < 512)      { src = Wq; ld = 512; nl = nn;       }
        else if (nn < 768) { src = Wk; ld = 256; nl = nn - 512; }
        else               { src = Wv; ld = 256; nl = nn - 768; }
        union { short8 s; uint4 u; } c;
        #pragma unroll
        for (int j = 0; j < 8; ++j) c.s[j] = (short)f2bf(src[(size_t)(k0+j)*ld + nl]);
        *reinterpret_cast<uint4*>(Wt + (size_t)nn*256 + k0) = c.u;
    } else if (eid < 40960) {
        int e2 = eid - 32768;
        int nn = e2 >> 5, k0 = (e2 & 31)*8;
        union { short8 s; uint4 u; } c;
        #pragma unroll
        for (int j = 0; j < 8; ++j) c.s[j] = (short)f2bf(Wo[(size_t)(k0+j)*256 + nn]);
        *reinterpret_cast<uint4*>(Wot + (size_t)nn*256 + k0) = c.u;
    }
}

// ---------------------------------------------------------------------------
// Kernel 1: MFMA projection. X(65536x256 fp32) @ W(256x1024) -> bf16 QGKV.
// Block = 128 tokens x all 1024 cols. A staged once frag-linear in LDS
// (fp32->bf16 on the fly); B frags read direct from L2-resident Wt.
// mfma(A=Wt-frag, B=X-frag) -> D: col=token=lane&15, row=n=(lane>>4)*4+reg.
// ---------------------------------------------------------------------------
__global__ void __launch_bounds__(256) proj_mfma_kernel(
    const float* __restrict__ x, const u16* __restrict__ Wt, u16* __restrict__ QGKV)
{
    __shared__ u16 AL[128*256];   // 64 KiB, frag-linear: (ks*8+rb)*512 + (g*16+r)*8 + j
    int tid = threadIdx.x;
    int rt  = blockIdx.x;         // 512 row-tiles of 128 tokens

    // ---- stage A (fp32 -> bf16, frag-linear) ----
    {
        int i  = tid >> 1;        // row 0..127
        int kg = tid & 1;         // k half
        int t  = rt*128 + i;
        int bw = t >> 9, h = t & 511, b = bw >> 6, w = bw & 63;
        const float* xr = x + ((size_t)((b*DH + h)*DW + w))*DC;
        int rb = i >> 4, r = i & 15;
        #pragma unroll
        for (int kk = 0; kk < 16; ++kk) {
            int k0 = kg*128 + kk*8;
            float4 f0 = *reinterpret_cast<const float4*>(xr + k0);
            float4 f1 = *reinterpret_cast<const float4*>(xr + k0 + 4);
            union { short8 s; uint4 u; } c;
            c.s[0]=(short)f2bf(f0.x); c.s[1]=(short)f2bf(f0.y);
            c.s[2]=(short)f2bf(f0.z); c.s[3]=(short)f2bf(f0.w);
            c.s[4]=(short)f2bf(f1.x); c.s[5]=(short)f2bf(f1.y);
            c.s[6]=(short)f2bf(f1.z); c.s[7]=(short)f2bf(f1.w);
            int ks = k0 >> 5, gg = (k0 >> 3) & 3;
            *reinterpret_cast<uint4*>(AL + (ks*8+rb)*512 + (gg*16+r)*8) = c.u;
        }
    }
    __syncthreads();

    int lane = tid & 63, wv = tid >> 6;
    int g = lane >> 4, lq = lane & 15;
    int rhalf = wv >> 1, cstrip = wv & 1;

    for (int ct = 0; ct < 8; ++ct) {
        int nbase = ct*128 + cstrip*64;
        f32x4 acc[4][4];          // [tf][nf]
        #pragma unroll
        for (int a = 0; a < 4; ++a)
            #pragma unroll
            for (int bb = 0; bb < 4; ++bb) acc[a][bb] = (f32x4){0.f,0.f,0.f,0.f};

        #pragma unroll
        for (int ks = 0; ks < 8; ++ks) {
            short8 wf[4], xf[4];
            #pragma unroll
            for (int nf = 0; nf < 4; ++nf) {
                union { uint4 u; short8 s; } c;
                c.u = *reinterpret_cast<const uint4*>(Wt + (size_t)(nbase + nf*16 + lq)*256 + ks*32 + g*8);
                wf[nf] = c.s;
            }
            #pragma unroll
            for (int tf = 0; tf < 4; ++tf) {
                union { uint4 u; short8 s; } c;
                c.u = *reinterpret_cast<const uint4*>(AL + (ks*8 + rhalf*4 + tf)*512 + lane*8);
                xf[tf] = c.s;
            }
            #pragma unroll
            for (int tf = 0; tf < 4; ++tf)
                #pragma unroll
                for (int nf = 0; nf < 4; ++nf)
                    acc[tf][nf] = __builtin_amdgcn_mfma_f32_16x16x32_bf16(wf[nf], xf[tf], acc[tf][nf], 0, 0, 0);
        }
        #pragma unroll
        for (int tf = 0; tf < 4; ++tf) {
            int trow = rt*128 + (rhalf*4 + tf)*16 + lq;
            u16* dst = QGKV + (size_t)trow*1024 + nbase;
            #pragma unroll
            for (int nf = 0; nf < 4; ++nf) {
                uint2 w2;
                w2.x = (u32)f2bf(acc[tf][nf][0]) | ((u32)f2bf(acc[tf][nf][1]) << 16);
                w2.y = (u32)f2bf(acc[tf][nf][2]) | ((u32)f2bf(acc[tf][nf][3]) << 16);
                *reinterpret_cast<uint2*>(dst + nf*16 + g*4) = w2;
            }
        }
    }
}

// ---------------------------------------------------------------------------
// Kernel 2: MFMA flash attention per (bw, head), with FUSED RMSNorm+RoPE.
// 8 waves x 64 q-rows, 32-key steps. Swapped QK^T -> q = lane&15 everywhere.
// LDS: KL 32K + VT 32K + QP 32K (Q-staging, then P-scratch) = 96 KiB.
// Output: o*sigmoid(gate), bf16, overwrites q columns.
// ---------------------------------------------------------------------------
__global__ void __launch_bounds__(512) attn_kernel(
    u16* __restrict__ QGKV,
    const float* __restrict__ qnw, const float* __restrict__ knw,
    const float* __restrict__ cosT, const float* __restrict__ sinT)
{
    __shared__ u16 KL[512*32];       // K frag-linear
    __shared__ u16 VT[32*512];       // V^T frag-linear
    __shared__ u16 QP[512*32];       // Q frag-linear, then P scratch (per-wave 2048 u16)

    int bid  = blockIdx.x;           // [0,1024)
    int bw   = bid >> 3, n = bid & 7;
    int tid  = threadIdx.x;
    int lane = tid & 63;
    int wv   = tid >> 6;
    int g    = lane >> 4;
    int lq   = lane & 15;

    // ---- stage: thread i owns row i: norm+rope Q,K; copy V^T ----
    {
        int i = tid;
        size_t tb = ((size_t)(bw*DH + i))*1024;
        int b = bw >> 6;
        int tbl = ((b*DH + i)*NHEADS + n)*HALFD;
        float cs[16], sn[16];
        #pragma unroll
        for (int j4 = 0; j4 < 4; ++j4) {
            float4 c4 = *reinterpret_cast<const float4*>(cosT + tbl + j4*4);
            float4 s4 = *reinterpret_cast<const float4*>(sinT + tbl + j4*4);
            cs[j4*4+0]=c4.x; cs[j4*4+1]=c4.y; cs[j4*4+2]=c4.z; cs[j4*4+3]=c4.w;
            sn[j4*4+0]=s4.x; sn[j4*4+1]=s4.y; sn[j4*4+2]=s4.z; sn[j4*4+3]=s4.w;
        }
        int rb = i >> 4, r = i & 15;
        #pragma unroll
        for (int which = 0; which < 2; ++which) {
            const u16* srcp = QGKV + tb + (which ? 512 : 0) + n*HDIM;
            const float* nw = which ? knw : qnw;
            u16* dstL = which ? KL : QP;
            uint4 rr[4];
            #pragma unroll
            for (int ii = 0; ii < 4; ++ii) rr[ii] = reinterpret_cast<const uint4*>(srcp)[ii];
            float v[32]; float ss = 0.f;
            const u32* rw = reinterpret_cast<const u32*>(rr);
            #pragma unroll
            for (int ii = 0; ii < 16; ++ii) {
                v[2*ii]   = bf_lo(rw[ii]);
                v[2*ii+1] = bf_hi(rw[ii]);
                ss += v[2*ii]*v[2*ii] + v[2*ii+1]*v[2*ii+1];
            }
            float rs = rsqrtf(ss*(1.0f/32.0f) + 1e-6f);
            #pragma unroll
            for (int d = 0; d < 32; ++d) v[d] *= rs * nw[d];
            #pragma unroll
            for (int j = 0; j < 16; ++j) {
                float e = v[2*j], o = v[2*j+1];
                v[2*j]   = e*cs[j] - o*sn[j];
                v[2*j+1] = e*sn[j] + o*cs[j];
            }
            #pragma unroll
            for (int gg = 0; gg < 4; ++gg) {
                uint4 u;
                u.x = (u32)f2bf(v[8*gg+0]) | ((u32)f2bf(v[8*gg+1]) << 16);
                u.y = (u32)f2bf(v[8*gg+2]) | ((u32)f2bf(v[8*gg+3]) << 16);
                u.z = (u32)f2bf(v[8*gg+4]) | ((u32)f2bf(v[8*gg+5]) << 16);
                u.w = (u32)f2bf(v[8*gg+6]) | ((u32)f2bf(v[8*gg+7]) << 16);
                *reinterpret_cast<uint4*>(dstL + rb*512 + gg*128 + r*8) = u;
            }
        }
        // V -> VT (transposed frag-linear)
        const uint4* vsrc = reinterpret_cast<const uint4*>(QGKV + tb + 768 + n*HDIM);
        uint4 vv[4];
        #pragma unroll
        for (int gg = 0; gg < 4; ++gg) vv[gg] = vsrc[gg];
        const u16* vp = reinterpret_cast<const u16*>(vv);
        int st = i >> 5, vg = (i >> 3) & 3, vj = i & 7;
        #pragma unroll
        for (int d = 0; d < 32; ++d) {
            VT[st*1024 + (d>>4)*512 + vg*128 + (d&15)*8 + vj] = vp[d];
        }
    }
    __syncthreads();

    // ---- load Q fragments from QP ----
    short8 qf[4];
    #pragma unroll
    for (int qt = 0; qt < 4; ++qt) {
        union { uint4 u; short8 s; } c;
        c.u = *reinterpret_cast<const uint4*>(QP + (wv*4 + qt)*512 + lane*8);
        qf[qt] = c.s;
    }
    __syncthreads();   // QP now becomes P scratch

    f32x4 oacc[4][2];
    float m_run[4], l_run[4];
    #pragma unroll
    for (int qt = 0; qt < 4; ++qt) {
        oacc[qt][0] = (f32x4){0.f,0.f,0.f,0.f};
        oacc[qt][1] = (f32x4){0.f,0.f,0.f,0.f};
        m_run[qt] = -3.0e38f;
        l_run[qt] = 0.f;
    }

    u16* PW = QP + wv*2048;                         // 64 rows x 32 keys
    const int sw = (lq ^ (lq >> 2)) & 3;
    const float CSC = 0.17677669529663687f * 1.4426950408889634f;  // scale*log2e

    for (int st = 0; st < 16; ++st) {
        short8 kf[2];
        #pragma unroll
        for (int kt = 0; kt < 2; ++kt) {
            union { uint4 u; short8 s; } c;
            c.u = *reinterpret_cast<const uint4*>(KL + (st*2 + kt)*512 + lane*8);
            kf[kt] = c.s;
        }
        #pragma unroll
        for (int qt = 0; qt < 4; ++qt) {
            f32x4 sf0 = __builtin_amdgcn_mfma_f32_16x16x32_bf16(kf[0], qf[qt], (f32x4){0.f,0.f,0.f,0.f}, 0, 0, 0);
            f32x4 sf1 = __builtin_amdgcn_mfma_f32_16x16x32_bf16(kf[1], qf[qt], (f32x4){0.f,0.f,0.f,0.f}, 0, 0, 0);
            float z[8];
            float tmax = -3.0e38f;
            #pragma unroll
            for (int r = 0; r < 4; ++r) {
                z[r]   = sf0[r]*CSC;
                z[4+r] = sf1[r]*CSC;
                tmax = fmaxf(tmax, fmaxf(z[r], z[4+r]));
            }
            tmax = fmaxf(tmax, __shfl_xor(tmax, 16));
            tmax = fmaxf(tmax, __shfl_xor(tmax, 32));
            float mo = m_run[qt];
            float mn = fmaxf(mo, tmax);
            float corr = __builtin_amdgcn_exp2f(mo - mn);
            m_run[qt] = mn;
            l_run[qt] *= corr;
            oacc[qt][0] *= corr;
            oacc[qt][1] *= corr;
            float p[8], ls = 0.f;
            #pragma unroll
            for (int ii = 0; ii < 8; ++ii) {
                p[ii] = __builtin_amdgcn_exp2f(z[ii] - mn);
                ls += p[ii];
            }
            l_run[qt] += ls;
            int row = qt*16 + lq;
            #pragma unroll
            for (int kt = 0; kt < 2; ++kt) {
                int ch = (kt*2 + (g >> 1)) ^ sw;
                uint2 w2;
                w2.x = pack_bf2(p[kt*4+0], p[kt*4+1]);
                w2.y = pack_bf2(p[kt*4+2], p[kt*4+3]);
                *reinterpret_cast<uint2*>(PW + row*32 + ch*8 + (g&1)*4) = w2;
            }
        }
        // ---- PV ----
        short8 va[2];
        #pragma unroll
        for (int df = 0; df < 2; ++df) {
            union { uint4 u; short8 s; } c;
            c.u = *reinterpret_cast<const uint4*>(VT + st*1024 + df*512 + lane*8);
            va[df] = c.s;
        }
        short8 pb[4];
        #pragma unroll
        for (int qt = 0; qt < 4; ++qt) {
            int row = qt*16 + lq;
            union { uint4 u; short8 s; } c;
            c.u = *reinterpret_cast<const uint4*>(PW + row*32 + (g ^ sw)*8);
            pb[qt] = c.s;
        }
        #pragma unroll
        for (int qt = 0; qt < 4; ++qt) {
            oacc[qt][0] = __builtin_amdgcn_mfma_f32_16x16x32_bf16(va[0], pb[qt], oacc[qt][0], 0, 0, 0);
            oacc[qt][1] = __builtin_amdgcn_mfma_f32_16x16x32_bf16(va[1], pb[qt], oacc[qt][1], 0, 0, 0);
        }
    }

    // ---- epilogue: normalize, gate, store (overwrites q columns) ----
    #pragma unroll
    for (int qt = 0; qt < 4; ++qt) {
        float lr = l_run[qt];
        lr += __shfl_xor(lr, 16);
        lr += __shfl_xor(lr, 32);
        float inv = 1.0f / lr;
        int t = bw*DH + wv*64 + qt*16 + lq;
        size_t tb = (size_t)t*1024;
        #pragma unroll
        for (int df = 0; df < 2; ++df) {
            int col = n*HDIM + 16*df + 4*g;
            ushort4 gv = *reinterpret_cast<const ushort4*>(QGKV + tb + 256 + col);
            u16 gr[4] = {gv.x, gv.y, gv.z, gv.w};
            ushort4 ov;
            u16 orr[4];
            #pragma unroll
            for (int r = 0; r < 4; ++r) {
                float o  = oacc[qt][df][r] * inv;
                float gf = bfu(gr[r]);
                float sg = 1.0f / (1.0f + __builtin_amdgcn_exp2f(-gf * 1.4426950408889634f));
                orr[r] = f2bf_fast(o * sg);
            }
            ov.x = orr[0]; ov.y = orr[1]; ov.z = orr[2]; ov.w = orr[3];
            *reinterpret_cast<ushort4*>(QGKV + tb + col) = ov;
        }
    }
}

// ---------------------------------------------------------------------------
// Kernel 3: MFMA output projection. AG(65536x256 bf16 @ QGKV ld 1024) @ Wo
// + bo -> fp32 out (scattered). Same structure as proj; N=256 (2 col-tiles).
// ---------------------------------------------------------------------------
__global__ void __launch_bounds__(256) outproj_mfma_kernel(
    const u16* __restrict__ QGKV, const u16* __restrict__ Wot,
    const float* __restrict__ bo, float* __restrict__ out)
{
    __shared__ u16 AL[128*256];   // 64 KiB frag-linear
    int tid = threadIdx.x;
    int rt  = blockIdx.x;

    {
        int i  = tid >> 1;
        int kg = tid & 1;
        const u16* arow = QGKV + (size_t)(rt*128 + i)*1024;
        int rb = i >> 4, r = i & 15;
        #pragma unroll
        for (int kk = 0; kk < 16; ++kk) {
            int k0 = kg*128 + kk*8;
            uint4 u = *reinterpret_cast<const uint4*>(arow + k0);
            int ks = k0 >> 5, gg = (k0 >> 3) & 3;
            *reinterpret_cast<uint4*>(AL + (ks*8+rb)*512 + (gg*16+r)*8) = u;
        }
    }
    __syncthreads();

    int lane = tid & 63, wv = tid >> 6;
    int g = lane >> 4, lq = lane & 15;
    int rhalf = wv >> 1, cstrip = wv & 1;

    for (int ct = 0; ct < 2; ++ct) {
        int nbase = ct*128 + cstrip*64;
        f32x4 acc[4][4];
        #pragma unroll
        for (int a = 0; a < 4; ++a)
            #pragma unroll
            for (int bb = 0; bb < 4; ++bb) acc[a][bb] = (f32x4){0.f,0.f,0.f,0.f};

        #pragma unroll
        for (int ks = 0; ks < 8; ++ks) {
            short8 wf[4], xf[4];
            #pragma unroll
            for (int nf = 0; nf < 4; ++nf) {
                union { uint4 u; short8 s; } c;
                c.u = *reinterpret_cast<const uint4*>(Wot + (size_t)(nbase + nf*16 + lq)*256 + ks*32 + g*8);
                wf[nf] = c.s;
            }
            #pragma unroll
            for (int tf = 0; tf < 4; ++tf) {
                union { uint4 u; short8 s; } c;
                c.u = *reinterpret_cast<const uint4*>(AL + (ks*8 + rhalf*4 + tf)*512 + lane*8);
                xf[tf] = c.s;
            }
            #pragma unroll
            for (int tf = 0; tf < 4; ++tf)
                #pragma unroll
                for (int nf = 0; nf < 4; ++nf)
                    acc[tf][nf] = __builtin_amdgcn_mfma_f32_16x16x32_bf16(wf[nf], xf[tf], acc[tf][nf], 0, 0, 0);
        }
        #pragma unroll
        for (int tf = 0; tf < 4; ++tf) {
            int trow = rt*128 + (rhalf*4 + tf)*16 + lq;
            int bw = trow >> 9, h = trow & 511, b = bw >> 6, w = bw & 63;
            float* orow = out + ((size_t)((b*DH + h)*DW + w))*DC;
            #pragma unroll
            for (int nf = 0; nf < 4; ++nf) {
                int nn = nbase + nf*16 + g*4;
                float4 bv = *reinterpret_cast<const float4*>(bo + nn);
                float4 res;
                res.x = acc[tf][nf][0] + bv.x;
                res.y = acc[tf][nf][1] + bv.y;
                res.z = acc[tf][nf][2] + bv.z;
                res.w = acc[tf][nf][3] + bv.w;
                *reinterpret_cast<float4*>(orow + nn) = res;
            }
        }
    }
}

// ---------------------------------------------------------------------------
extern "C" void kernel_launch(void* const* d_in, const int* in_sizes, int n_in,
                              void* d_out, int out_size, void* d_ws, size_t ws_size,
                              hipStream_t stream)
{
    const float* x      = (const float*)d_in[0];
    const float* pos    = (const float*)d_in[1];
    const float* Wq     = (const float*)d_in[2];
    const float* Wk     = (const float*)d_in[3];
    const float* Wv     = (const float*)d_in[4];
    const float* Wo     = (const float*)d_in[5];
    const float* bo     = (const float*)d_in[6];
    const float* qnw    = (const float*)d_in[7];
    const float* knw    = (const float*)d_in[8];
    const float* rope_w = (const float*)d_in[9];
    const float* rope_b = (const float*)d_in[10];
    float* out = (float*)d_out;

    char* wsp = (char*)d_ws;
    u16*   QGKV = (u16*)wsp;                                  // 128 MiB
    float* cosT = (float*)(wsp + (size_t)NTOK*1024*2);        // 512 KiB
    float* sinT = cosT + DB*DH*NHEADS*HALFD;                  // 512 KiB
    u16*   Wt   = (u16*)(sinT + DB*DH*NHEADS*HALFD);          // 512 KiB
    u16*   Wot  = Wt + 1024*256;                              // 128 KiB

    rope_table_kernel  <<<dim3(512),  dim3(256), 0, stream>>>(pos, rope_w, rope_b, cosT, sinT);
    wconv_kernel       <<<dim3(160),  dim3(256), 0, stream>>>(Wq, Wk, Wv, Wo, Wt, Wot);
    proj_mfma_kernel   <<<dim3(512),  dim3(256), 0, stream>>>(x, Wt, QGKV);
    attn_kernel        <<<dim3(1024), dim3(512), 0, stream>>>(QGKV, qnw, knw, cosT, sinT);
    outproj_mfma_kernel<<<dim3(512),  dim3(256), 0, stream>>>(QGKV, Wot, bo, out);
}

// Round 4
// 238.566 us; speedup vs baseline: 7.2116x; 1.1884x over previous
//
#include <hip/hip_runtime.h>
#include <hip/hip_bf16.h>
#include <math.h>

#define NHEADS 8
#define HDIM   32
#define HALFD  16
#define DB     2
#define DH     512
#define DW     64
#define DC     256
#define NTOK   (DB*DW*DH)   /* 65536 tokens, t = (b*64+w)*512 + h */

typedef unsigned short u16;
typedef unsigned int   u32;
typedef short short8 __attribute__((ext_vector_type(8)));
typedef float f32x4  __attribute__((ext_vector_type(4)));

__device__ __forceinline__ float bf_lo(u32 u){ union{u32 i; float f;} c; c.i = u << 16; return c.f; }
__device__ __forceinline__ float bf_hi(u32 u){ union{u32 i; float f;} c; c.i = u & 0xffff0000u; return c.f; }
__device__ __forceinline__ float bfu(u16 u){ union{u32 i; float f;} c; c.i = ((u32)u) << 16; return c.f; }
__device__ __forceinline__ u16 f2bf(float f){
    u32 x = __float_as_uint(f);
    u32 r = (x + 0x7fffu + ((x >> 16) & 1u)) >> 16;   // RTN-even
    return (u16)r;
}
__device__ __forceinline__ u16 f2bf_fast(float f){
    return (u16)((__float_as_uint(f) + 0x8000u) >> 16);
}
// single-instruction pack: lo=bf16(a), hi=bf16(b)
__device__ __forceinline__ u32 cvtpk(float a, float b){
    u32 r; asm("v_cvt_pk_bf16_f32 %0, %1, %2" : "=v"(r) : "v"(a), "v"(b)); return r;
}

// ---------------------------------------------------------------------------
// Kernel 0: prep = rope cos/sin table (blocks 0..511) + weight transpose
// (blocks 512..671).
// ---------------------------------------------------------------------------
__global__ void __launch_bounds__(256) prep_kernel(
    const float* __restrict__ pos, const float* __restrict__ rope_w,
    const float* __restrict__ rope_b, float* __restrict__ cosT, float* __restrict__ sinT,
    const float* __restrict__ Wq, const float* __restrict__ Wk,
    const float* __restrict__ Wv, const float* __restrict__ Wo,
    u16* __restrict__ Wt, u16* __restrict__ Wot)
{
    int bid = blockIdx.x;
    if (bid < 512) {
        int id = bid * 256 + threadIdx.x;              // [0, 131072)
        int j = id & 15;
        int n = (id >> 4) & 7;
        int h = (id >> 7) & 511;
        int b = id >> 16;
        const float* pp = pos + (size_t)(b*DH + h)*4;
        float p = pp[0]*rope_w[0] + pp[1]*rope_w[1] + pp[2]*rope_w[2] + pp[3]*rope_w[3] + rope_b[0];
        int fi = n*HALFD + j;
        float freq = expf(-12.0f + (float)fi * (12.0f/127.0f));
        float ang = p * freq;                           // P_SCALE = 1
        cosT[id] = cosf(ang);
        sinT[id] = sinf(ang);
    } else {
        int eid = (bid - 512)*256 + threadIdx.x;       // [0, 40960)
        if (eid < 32768) {
            int nn = eid >> 5, k0 = (eid & 31)*8;
            const float* src; int ld, nl;
            if (nn < 512)      { src = Wq; ld = 512; nl = nn;       }
            else if (nn < 768) { src = Wk; ld = 256; nl = nn - 512; }
            else               { src = Wv; ld = 256; nl = nn - 768; }
            union { short8 s; uint4 u; } c;
            #pragma unroll
            for (int j = 0; j < 8; ++j) c.s[j] = (short)f2bf(src[(size_t)(k0+j)*ld + nl]);
            *reinterpret_cast<uint4*>(Wt + (size_t)nn*256 + k0) = c.u;
        } else {
            int e2 = eid - 32768;
            int nn = e2 >> 5, k0 = (e2 & 31)*8;
            union { short8 s; uint4 u; } c;
            #pragma unroll
            for (int j = 0; j < 8; ++j) c.s[j] = (short)f2bf(Wo[(size_t)(k0+j)*256 + nn]);
            *reinterpret_cast<uint4*>(Wot + (size_t)nn*256 + k0) = c.u;
        }
    }
}

// ---------------------------------------------------------------------------
// Kernel 1: MFMA projection. X(65536x256 fp32) @ W(256x1024) -> bf16 QGKV.
// ---------------------------------------------------------------------------
__global__ void __launch_bounds__(256) proj_mfma_kernel(
    const float* __restrict__ x, const u16* __restrict__ Wt, u16* __restrict__ QGKV)
{
    __shared__ u16 AL[128*256];   // 64 KiB, frag-linear
    int tid = threadIdx.x;
    int rt  = blockIdx.x;         // 512 row-tiles of 128 tokens

    {
        int i  = tid >> 1;        // row 0..127
        int kg = tid & 1;         // k half
        int t  = rt*128 + i;
        int bw = t >> 9, h = t & 511, b = bw >> 6, w = bw & 63;
        const float* xr = x + ((size_t)((b*DH + h)*DW + w))*DC;
        int rb = i >> 4, r = i & 15;
        #pragma unroll
        for (int kk = 0; kk < 16; ++kk) {
            int k0 = kg*128 + kk*8;
            float4 f0 = *reinterpret_cast<const float4*>(xr + k0);
            float4 f1 = *reinterpret_cast<const float4*>(xr + k0 + 4);
            union { short8 s; uint4 u; } c;
            c.s[0]=(short)f2bf(f0.x); c.s[1]=(short)f2bf(f0.y);
            c.s[2]=(short)f2bf(f0.z); c.s[3]=(short)f2bf(f0.w);
            c.s[4]=(short)f2bf(f1.x); c.s[5]=(short)f2bf(f1.y);
            c.s[6]=(short)f2bf(f1.z); c.s[7]=(short)f2bf(f1.w);
            int ks = k0 >> 5, gg = (k0 >> 3) & 3;
            *reinterpret_cast<uint4*>(AL + (ks*8+rb)*512 + (gg*16+r)*8) = c.u;
        }
    }
    __syncthreads();

    int lane = tid & 63, wv = tid >> 6;
    int g = lane >> 4, lq = lane & 15;
    int rhalf = wv >> 1, cstrip = wv & 1;

    for (int ct = 0; ct < 8; ++ct) {
        int nbase = ct*128 + cstrip*64;
        f32x4 acc[4][4];          // [tf][nf]
        #pragma unroll
        for (int a = 0; a < 4; ++a)
            #pragma unroll
            for (int bb = 0; bb < 4; ++bb) acc[a][bb] = (f32x4){0.f,0.f,0.f,0.f};

        #pragma unroll
        for (int ks = 0; ks < 8; ++ks) {
            short8 wf[4], xf[4];
            #pragma unroll
            for (int nf = 0; nf < 4; ++nf) {
                union { uint4 u; short8 s; } c;
                c.u = *reinterpret_cast<const uint4*>(Wt + (size_t)(nbase + nf*16 + lq)*256 + ks*32 + g*8);
                wf[nf] = c.s;
            }
            #pragma unroll
            for (int tf = 0; tf < 4; ++tf) {
                union { uint4 u; short8 s; } c;
                c.u = *reinterpret_cast<const uint4*>(AL + (ks*8 + rhalf*4 + tf)*512 + lane*8);
                xf[tf] = c.s;
            }
            #pragma unroll
            for (int tf = 0; tf < 4; ++tf)
                #pragma unroll
                for (int nf = 0; nf < 4; ++nf)
                    acc[tf][nf] = __builtin_amdgcn_mfma_f32_16x16x32_bf16(wf[nf], xf[tf], acc[tf][nf], 0, 0, 0);
        }
        #pragma unroll
        for (int tf = 0; tf < 4; ++tf) {
            int trow = rt*128 + (rhalf*4 + tf)*16 + lq;
            u16* dst = QGKV + (size_t)trow*1024 + nbase;
            #pragma unroll
            for (int nf = 0; nf < 4; ++nf) {
                uint2 w2;
                w2.x = (u32)f2bf(acc[tf][nf][0]) | ((u32)f2bf(acc[tf][nf][1]) << 16);
                w2.y = (u32)f2bf(acc[tf][nf][2]) | ((u32)f2bf(acc[tf][nf][3]) << 16);
                *reinterpret_cast<uint2*>(dst + nf*16 + g*4) = w2;
            }
        }
    }
}

// ---------------------------------------------------------------------------
// Kernel 2: MFMA flash attention per (bw, head), fused RMSNorm+RoPE.
// 8 waves x 64 q-rows, 32-key steps. Swapped QK^T -> q = lane&15 everywhere.
// NO-MAX softmax: |s| <= 32*scale (rows RMS-normalized) -> p = exp2(s*CSC)
// directly, CSC folded into Q at staging. V stored row-major in two d-planes,
// A-frags fetched with ds_read_b64_tr_b16 (HW transpose).
// ---------------------------------------------------------------------------
__global__ void __launch_bounds__(512) attn_kernel(
    u16* __restrict__ QGKV,
    const float* __restrict__ qnw, const float* __restrict__ knw,
    const float* __restrict__ cosT, const float* __restrict__ sinT)
{
    __shared__ u16 KL[512*32];       // K frag-linear, 32 KiB
    __shared__ u16 VL[2*8192];       // V planes: [df][key][dd], 32 KiB
    __shared__ u16 QP[512*32];       // Q frag-linear, then per-wave P scratch

    int bid  = blockIdx.x;           // [0,1024)
    int bw   = bid >> 3, n = bid & 7;
    int tid  = threadIdx.x;
    int lane = tid & 63;
    int wv   = tid >> 6;
    int g    = lane >> 4;
    int lq   = lane & 15;
    const float CSC = 0.17677669529663687f * 1.4426950408889634f;  // scale*log2e

    // ---- stage: thread i owns row i: norm+rope Q,K; copy V planes ----
    {
        int i = tid;
        size_t tb = ((size_t)(bw*DH + i))*1024;
        int b = bw >> 6;
        int tbl = ((b*DH + i)*NHEADS + n)*HALFD;
        float cs[16], sn[16];
        #pragma unroll
        for (int j4 = 0; j4 < 4; ++j4) {
            float4 c4 = *reinterpret_cast<const float4*>(cosT + tbl + j4*4);
            float4 s4 = *reinterpret_cast<const float4*>(sinT + tbl + j4*4);
            cs[j4*4+0]=c4.x; cs[j4*4+1]=c4.y; cs[j4*4+2]=c4.z; cs[j4*4+3]=c4.w;
            sn[j4*4+0]=s4.x; sn[j4*4+1]=s4.y; sn[j4*4+2]=s4.z; sn[j4*4+3]=s4.w;
        }
        int rb = i >> 4, r = i & 15;
        #pragma unroll
        for (int which = 0; which < 2; ++which) {
            const u16* srcp = QGKV + tb + (which ? 512 : 0) + n*HDIM;
            const float* nw = which ? knw : qnw;
            u16* dstL = which ? KL : QP;
            uint4 rr[4];
            #pragma unroll
            for (int ii = 0; ii < 4; ++ii) rr[ii] = reinterpret_cast<const uint4*>(srcp)[ii];
            float v[32]; float ss = 0.f;
            const u32* rw = reinterpret_cast<const u32*>(rr);
            #pragma unroll
            for (int ii = 0; ii < 16; ++ii) {
                v[2*ii]   = bf_lo(rw[ii]);
                v[2*ii+1] = bf_hi(rw[ii]);
                ss += v[2*ii]*v[2*ii] + v[2*ii+1]*v[2*ii+1];
            }
            float rs = rsqrtf(ss*(1.0f/32.0f) + 1e-6f);
            if (which == 0) rs *= CSC;                    // fold softmax scale into Q
            #pragma unroll
            for (int d = 0; d < 32; ++d) v[d] *= rs * nw[d];
            #pragma unroll
            for (int j = 0; j < 16; ++j) {
                float e = v[2*j], o = v[2*j+1];
                v[2*j]   = e*cs[j] - o*sn[j];
                v[2*j+1] = e*sn[j] + o*cs[j];
            }
            #pragma unroll
            for (int gg = 0; gg < 4; ++gg) {
                uint4 u;
                u.x = (u32)f2bf(v[8*gg+0]) | ((u32)f2bf(v[8*gg+1]) << 16);
                u.y = (u32)f2bf(v[8*gg+2]) | ((u32)f2bf(v[8*gg+3]) << 16);
                u.z = (u32)f2bf(v[8*gg+4]) | ((u32)f2bf(v[8*gg+5]) << 16);
                u.w = (u32)f2bf(v[8*gg+6]) | ((u32)f2bf(v[8*gg+7]) << 16);
                *reinterpret_cast<uint4*>(dstL + rb*512 + gg*128 + r*8) = u;
            }
        }
        // V: row-major into two 16-wide d-planes (contiguous b128 writes)
        const uint4* vsrc = reinterpret_cast<const uint4*>(QGKV + tb + 768 + n*HDIM);
        uint4 v0 = vsrc[0], v1 = vsrc[1], v2 = vsrc[2], v3 = vsrc[3];
        *reinterpret_cast<uint4*>(VL + i*16)          = v0;   // d 0..7
        *reinterpret_cast<uint4*>(VL + i*16 + 8)      = v1;   // d 8..15
        *reinterpret_cast<uint4*>(VL + 8192 + i*16)   = v2;   // d 16..23
        *reinterpret_cast<uint4*>(VL + 8192 + i*16+8) = v3;   // d 24..31
    }
    __syncthreads();

    // ---- load Q fragments from QP (wave-private region) ----
    short8 qf[4];
    #pragma unroll
    for (int qt = 0; qt < 4; ++qt) {
        union { uint4 u; short8 s; } c;
        c.u = *reinterpret_cast<const uint4*>(QP + (wv*4 + qt)*512 + lane*8);
        qf[qt] = c.s;
    }
    // (no barrier: P-scratch region below == this wave's own Q region; DS ops
    //  from one wave complete in order)

    f32x4 oacc[4][2];
    float l_run[4];
    #pragma unroll
    for (int qt = 0; qt < 4; ++qt) {
        oacc[qt][0] = (f32x4){0.f,0.f,0.f,0.f};
        oacc[qt][1] = (f32x4){0.f,0.f,0.f,0.f};
        l_run[qt] = 0.f;
    }

    u16* PW = QP + wv*2048;                         // 64 rows x 32 keys
    const int sw = (lq ^ (lq >> 2)) & 3;
    const u32 vbase = (u32)(uintptr_t)VL + (u32)(lq*8 + g*256);

    for (int st = 0; st < 16; ++st) {
        short8 kf[2];
        #pragma unroll
        for (int kt = 0; kt < 2; ++kt) {
            union { uint4 u; short8 s; } c;
            c.u = *reinterpret_cast<const uint4*>(KL + (st*2 + kt)*512 + lane*8);
            kf[kt] = c.s;
        }
        // issue V transpose-reads early (results consumed after lgkmcnt(0))
        uint2 v00, v01, v10, v11;
        {
            u32 ta = vbase + (u32)(st*1024);
            asm volatile("ds_read_b64_tr_b16 %0, %4\n\t"
                         "ds_read_b64_tr_b16 %1, %4 offset:128\n\t"
                         "ds_read_b64_tr_b16 %2, %4 offset:16384\n\t"
                         "ds_read_b64_tr_b16 %3, %4 offset:16512"
                         : "=v"(v00), "=v"(v01), "=v"(v10), "=v"(v11)
                         : "v"(ta));
        }
        #pragma unroll
        for (int qt = 0; qt < 4; ++qt) {
            f32x4 sf0 = __builtin_amdgcn_mfma_f32_16x16x32_bf16(kf[0], qf[qt], (f32x4){0.f,0.f,0.f,0.f}, 0, 0, 0);
            f32x4 sf1 = __builtin_amdgcn_mfma_f32_16x16x32_bf16(kf[1], qf[qt], (f32x4){0.f,0.f,0.f,0.f}, 0, 0, 0);
            float p0 = __builtin_amdgcn_exp2f(sf0[0]);
            float p1 = __builtin_amdgcn_exp2f(sf0[1]);
            float p2 = __builtin_amdgcn_exp2f(sf0[2]);
            float p3 = __builtin_amdgcn_exp2f(sf0[3]);
            float p4 = __builtin_amdgcn_exp2f(sf1[0]);
            float p5 = __builtin_amdgcn_exp2f(sf1[1]);
            float p6 = __builtin_amdgcn_exp2f(sf1[2]);
            float p7 = __builtin_amdgcn_exp2f(sf1[3]);
            l_run[qt] += ((p0+p1)+(p2+p3)) + ((p4+p5)+(p6+p7));
            int row = qt*16 + lq;
            int ch0 = ((g >> 1)    ) ^ sw;
            int ch1 = ((g >> 1) + 2) ^ sw;
            uint2 w0, w1;
            w0.x = cvtpk(p0, p1); w0.y = cvtpk(p2, p3);
            w1.x = cvtpk(p4, p5); w1.y = cvtpk(p6, p7);
            *reinterpret_cast<uint2*>(PW + row*32 + ch0*8 + (g&1)*4) = w0;
            *reinterpret_cast<uint2*>(PW + row*32 + ch1*8 + (g&1)*4) = w1;
        }
        short8 pb[4];
        #pragma unroll
        for (int qt = 0; qt < 4; ++qt) {
            int row = qt*16 + lq;
            union { uint4 u; short8 s; } c;
            c.u = *reinterpret_cast<const uint4*>(PW + row*32 + (g ^ sw)*8);
            pb[qt] = c.s;
        }
        asm volatile("s_waitcnt lgkmcnt(0)" ::: "memory");
        __builtin_amdgcn_sched_barrier(0);
        union { uint4 u; short8 s; } va0, va1;
        va0.u = make_uint4(v00.x, v00.y, v01.x, v01.y);
        va1.u = make_uint4(v10.x, v10.y, v11.x, v11.y);
        #pragma unroll
        for (int qt = 0; qt < 4; ++qt) {
            oacc[qt][0] = __builtin_amdgcn_mfma_f32_16x16x32_bf16(va0.s, pb[qt], oacc[qt][0], 0, 0, 0);
            oacc[qt][1] = __builtin_amdgcn_mfma_f32_16x16x32_bf16(va1.s, pb[qt], oacc[qt][1], 0, 0, 0);
        }
    }

    // ---- epilogue: normalize, gate, store (overwrites q columns) ----
    #pragma unroll
    for (int qt = 0; qt < 4; ++qt) {
        float lr = l_run[qt];
        lr += __shfl_xor(lr, 16);
        lr += __shfl_xor(lr, 32);
        float inv = 1.0f / lr;
        int t = bw*DH + wv*64 + qt*16 + lq;
        size_t tb = (size_t)t*1024;
        #pragma unroll
        for (int df = 0; df < 2; ++df) {
            int col = n*HDIM + 16*df + 4*g;
            ushort4 gv = *reinterpret_cast<const ushort4*>(QGKV + tb + 256 + col);
            u16 gr[4] = {gv.x, gv.y, gv.z, gv.w};
            ushort4 ov;
            u16 orr[4];
            #pragma unroll
            for (int r = 0; r < 4; ++r) {
                float o  = oacc[qt][df][r] * inv;
                float gf = bfu(gr[r]);
                float sg = 1.0f / (1.0f + __builtin_amdgcn_exp2f(-gf * 1.4426950408889634f));
                orr[r] = f2bf_fast(o * sg);
            }
            ov.x = orr[0]; ov.y = orr[1]; ov.z = orr[2]; ov.w = orr[3];
            *reinterpret_cast<ushort4*>(QGKV + tb + col) = ov;
        }
    }
}

// ---------------------------------------------------------------------------
// Kernel 3: MFMA output projection. AG(65536x256 bf16 @ QGKV ld 1024) @ Wo
// + bo -> fp32 out (scattered).
// ---------------------------------------------------------------------------
__global__ void __launch_bounds__(256) outproj_mfma_kernel(
    const u16* __restrict__ QGKV, const u16* __restrict__ Wot,
    const float* __restrict__ bo, float* __restrict__ out)
{
    __shared__ u16 AL[128*256];   // 64 KiB frag-linear
    int tid = threadIdx.x;
    int rt  = blockIdx.x;

    {
        int i  = tid >> 1;
        int kg = tid & 1;
        const u16* arow = QGKV + (size_t)(rt*128 + i)*1024;
        int rb = i >> 4, r = i & 15;
        #pragma unroll
        for (int kk = 0; kk < 16; ++kk) {
            int k0 = kg*128 + kk*8;
            uint4 u = *reinterpret_cast<const uint4*>(arow + k0);
            int ks = k0 >> 5, gg = (k0 >> 3) & 3;
            *reinterpret_cast<uint4*>(AL + (ks*8+rb)*512 + (gg*16+r)*8) = u;
        }
    }
    __syncthreads();

    int lane = tid & 63, wv = tid >> 6;
    int g = lane >> 4, lq = lane & 15;
    int rhalf = wv >> 1, cstrip = wv & 1;

    for (int ct = 0; ct < 2; ++ct) {
        int nbase = ct*128 + cstrip*64;
        f32x4 acc[4][4];
        #pragma unroll
        for (int a = 0; a < 4; ++a)
            #pragma unroll
            for (int bb = 0; bb < 4; ++bb) acc[a][bb] = (f32x4){0.f,0.f,0.f,0.f};

        #pragma unroll
        for (int ks = 0; ks < 8; ++ks) {
            short8 wf[4], xf[4];
            #pragma unroll
            for (int nf = 0; nf < 4; ++nf) {
                union { uint4 u; short8 s; } c;
                c.u = *reinterpret_cast<const uint4*>(Wot + (size_t)(nbase + nf*16 + lq)*256 + ks*32 + g*8);
                wf[nf] = c.s;
            }
            #pragma unroll
            for (int tf = 0; tf < 4; ++tf) {
                union { uint4 u; short8 s; } c;
                c.u = *reinterpret_cast<const uint4*>(AL + (ks*8 + rhalf*4 + tf)*512 + lane*8);
                xf[tf] = c.s;
            }
            #pragma unroll
            for (int tf = 0; tf < 4; ++tf)
                #pragma unroll
                for (int nf = 0; nf < 4; ++nf)
                    acc[tf][nf] = __builtin_amdgcn_mfma_f32_16x16x32_bf16(wf[nf], xf[tf], acc[tf][nf], 0, 0, 0);
        }
        #pragma unroll
        for (int tf = 0; tf < 4; ++tf) {
            int trow = rt*128 + (rhalf*4 + tf)*16 + lq;
            int bw = trow >> 9, h = trow & 511, b = bw >> 6, w = bw & 63;
            float* orow = out + ((size_t)((b*DH + h)*DW + w))*DC;
            #pragma unroll
            for (int nf = 0; nf < 4; ++nf) {
                int nn = nbase + nf*16 + g*4;
                float4 bv = *reinterpret_cast<const float4*>(bo + nn);
                float4 res;
                res.x = acc[tf][nf][0] + bv.x;
                res.y = acc[tf][nf][1] + bv.y;
                res.z = acc[tf][nf][2] + bv.z;
                res.w = acc[tf][nf][3] + bv.w;
                *reinterpret_cast<float4*>(orow + nn) = res;
            }
        }
    }
}

// ---------------------------------------------------------------------------
extern "C" void kernel_launch(void* const* d_in, const int* in_sizes, int n_in,
                              void* d_out, int out_size, void* d_ws, size_t ws_size,
                              hipStream_t stream)
{
    const float* x      = (const float*)d_in[0];
    const float* pos    = (const float*)d_in[1];
    const float* Wq     = (const float*)d_in[2];
    const float* Wk     = (const float*)d_in[3];
    const float* Wv     = (const float*)d_in[4];
    const float* Wo     = (const float*)d_in[5];
    const float* bo     = (const float*)d_in[6];
    const float* qnw    = (const float*)d_in[7];
    const float* knw    = (const float*)d_in[8];
    const float* rope_w = (const float*)d_in[9];
    const float* rope_b = (const float*)d_in[10];
    float* out = (float*)d_out;

    char* wsp = (char*)d_ws;
    u16*   QGKV = (u16*)wsp;                                  // 128 MiB
    float* cosT = (float*)(wsp + (size_t)NTOK*1024*2);        // 512 KiB
    float* sinT = cosT + DB*DH*NHEADS*HALFD;                  // 512 KiB
    u16*   Wt   = (u16*)(sinT + DB*DH*NHEADS*HALFD);          // 512 KiB
    u16*   Wot  = Wt + 1024*256;                              // 128 KiB

    prep_kernel        <<<dim3(672),  dim3(256), 0, stream>>>(pos, rope_w, rope_b, cosT, sinT,
                                                              Wq, Wk, Wv, Wo, Wt, Wot);
    proj_mfma_kernel   <<<dim3(512),  dim3(256), 0, stream>>>(x, Wt, QGKV);
    attn_kernel        <<<dim3(1024), dim3(512), 0, stream>>>(QGKV, qnw, knw, cosT, sinT);
    outproj_mfma_kernel<<<dim3(512),  dim3(256), 0, stream>>>(QGKV, Wot, bo, out);
}